// Round 6
// baseline (564.473 us; speedup 1.0000x reference)
//
#include <hip/hip_runtime.h>
#include <cstdint>
#include <cstddef>

#define FEAT 512
#define HID 256
#define CLS 40
#define EPS 1e-5f

typedef __attribute__((ext_vector_type(8))) short short8;
typedef __attribute__((ext_vector_type(4))) float f32x4v;

// ---------------- helpers ----------------

__device__ __forceinline__ unsigned short f2bf(float f) {
    union { float f; unsigned u; } v; v.f = f;
    unsigned r = v.u + 0x7FFF + ((v.u >> 16) & 1);   // round-to-nearest-even
    return (unsigned short)(r >> 16);
}
__device__ __forceinline__ float bf2f(unsigned short h) {
    union { unsigned u; float f; } v; v.u = ((unsigned)h) << 16;
    return v.f;
}

typedef const __attribute__((address_space(1))) unsigned int* gas_ptr;
typedef __attribute__((address_space(3))) unsigned int* las_ptr;
__device__ __forceinline__ void lds_load16(const void* g, void* l) {
    __builtin_amdgcn_global_load_lds((gas_ptr)g, (las_ptr)l, 16, 0, 0);
}

__device__ __forceinline__ float4 f4add(float4 a, float4 b) {
    return make_float4(a.x + b.x, a.y + b.y, a.z + b.z, a.w + b.w);
}

// accumulate a bf16x4 row fragment into a float4
__device__ __forceinline__ void accum_bf4(float4& a, ushort4 v) {
    a.x += bf2f(v.x); a.y += bf2f(v.y); a.z += bf2f(v.z); a.w += bf2f(v.w);
}

// ---------------- preprocessing: degree, CSR build ----------------

__global__ void zero_kernel(int* counts, int* fillpos, int n) {
    int i = blockIdx.x * 256 + threadIdx.x;
    if (i < n) { counts[i] = 0; fillpos[i] = 0; }
}

__global__ void hist_kernel(const int* __restrict__ dst, int* __restrict__ counts, int E) {
    int e = blockIdx.x * 256 + threadIdx.x;
    if (e < E) atomicAdd(&counts[dst[e]], 1);
}

__global__ void scan_block_kernel(const int* __restrict__ counts, int* __restrict__ row_ptr,
                                  int* __restrict__ blocksums, int n) {
    __shared__ int s[256];
    int tid = threadIdx.x;
    int i = blockIdx.x * 256 + tid;
    int v = (i < n) ? counts[i] : 0;
    s[tid] = v; __syncthreads();
    for (int off = 1; off < 256; off <<= 1) {
        int t = (tid >= off) ? s[tid - off] : 0;
        __syncthreads();
        s[tid] += t;
        __syncthreads();
    }
    if (i < n) row_ptr[i] = s[tid] - v;
    if (tid == 255) blocksums[blockIdx.x] = s[255];
}

__global__ void scan_sums_kernel(const int* __restrict__ blocksums, int* __restrict__ blockoffs, int nb) {
    __shared__ int s[256];
    int tid = threadIdx.x;
    int v = (tid < nb) ? blocksums[tid] : 0;
    s[tid] = v; __syncthreads();
    for (int off = 1; off < 256; off <<= 1) {
        int t = (tid >= off) ? s[tid - off] : 0;
        __syncthreads();
        s[tid] += t;
        __syncthreads();
    }
    blockoffs[tid] = s[tid] - v;
}

__global__ void finalize_rowptr_kernel(int* __restrict__ row_ptr, const int* __restrict__ blockoffs,
                                       const int* __restrict__ counts, float* __restrict__ inv_sqrt,
                                       int n, int E) {
    int i = blockIdx.x * 256 + threadIdx.x;
    if (i < n) {
        row_ptr[i] += blockoffs[i >> 8];
        inv_sqrt[i] = rsqrtf((float)(counts[i] + 1));
    }
    if (i == 0) row_ptr[n] = E;
}

__global__ void fill_kernel(const int* __restrict__ src, const int* __restrict__ dst,
                            const int* __restrict__ row_ptr, int* __restrict__ fillpos,
                            int* __restrict__ src_sorted, int E) {
    int e = blockIdx.x * 256 + threadIdx.x;
    if (e < E) {
        int d = dst[e];
        int pos = row_ptr[d] + atomicAdd(&fillpos[d], 1);
        src_sorted[pos] = src[e];
    }
}

// ---------------- weight split+transpose: W[K][Ncol] fp32 -> Wt_hi/lo [Ncol][K] bf16 ----------------

__global__ void cvt_w_kernel(const float* __restrict__ W, unsigned short* __restrict__ hi,
                             unsigned short* __restrict__ lo, int K, int Ncol) {
    int idx = blockIdx.x * 256 + threadIdx.x;
    if (idx >= K * Ncol) return;
    int k = idx / Ncol, n = idx % Ncol;
    float f = W[idx];
    unsigned short h = f2bf(f);
    hi[(size_t)n * K + k] = h;
    lo[(size_t)n * K + k] = f2bf(f - bf2f(h));
}

// ---------------- x fp32 -> bf16 (memory-bound pass; each thread converts 8) ----------------

__global__ __launch_bounds__(256) void cvt_x_kernel(const float* __restrict__ x,
                                                    unsigned short* __restrict__ out, int total8) {
    int i = blockIdx.x * 256 + threadIdx.x;
    if (i >= total8) return;
    const float4* xp = (const float4*)x;
    float4 a = xp[2 * i], b = xp[2 * i + 1];
    float f[8] = {a.x, a.y, a.z, a.w, b.x, b.y, b.z, b.w};
    short8 h;
#pragma unroll
    for (int j = 0; j < 8; ++j) h[j] = (short)f2bf(f[j]);
    ((short8*)out)[i] = h;
}

// ---------------- split-bf16 MFMA GEMM ----------------
// C[row][col] = bf16( (A @ W)[row][col] * inv_sqrt[row] ), W = Whi+Wlo.
// A_SPLIT=true : A = Ahi+Alo (3 MFMAs/pair, layer 2).
// A_SPLIT=false: A = single bf16 (2 MFMAs/pair, layer 1; pre-converted by cvt_x).
// 128x128 tile, BK=32, 4 waves, each wave 64x64 = 4x4 frags of 16x16x32.
// LDS fragment-linear per 16-row block: elem(m^,k_local) at 8*m^ + 128*(k_local>>3) + (k_local&7)
//   => a frag read is lane*16B contiguous (ds_read_b128, conflict-free).
// Wt is [n][k] so B-fragments are contiguous 16B runs too. All staging via global_load_lds w=16.

template<bool A_SPLIT>
__global__ __launch_bounds__(256) void gemm_mfma_kernel(
        const unsigned short* __restrict__ gAhi, const unsigned short* __restrict__ gAlo,
        const unsigned short* __restrict__ Wthi, const unsigned short* __restrict__ Wtlo,
        const float* __restrict__ inv_sqrt, unsigned short* __restrict__ C,
        int M, int K, int Ncol) {
    __shared__ unsigned short AhiL[4096];
    __shared__ unsigned short AloL[A_SPLIT ? 4096 : 4];
    __shared__ unsigned short BhiL[4096], BloL[4096];
    const int tid  = threadIdx.x;
    const int lane = tid & 63;
    const int w    = tid >> 6;        // wave 0..3
    const int wr   = w >> 1, wc = w & 1;
    const int lm   = lane & 15;
    const int lk8  = (lane >> 4) * 8;
    const int bm   = blockIdx.x * 128;
    const int bn   = blockIdx.y * 128;

    f32x4v acc[4][4] = {};

    // --- B staging pointers (wave fills n-blocks 2w, 2w+1, hi+lo) ---
    int nc0 = bn + 16 * (2 * w) + lm;
    int nc1 = bn + 16 * (2 * w + 1) + lm;
    const unsigned short* gB_h0 = Wthi + (size_t)nc0 * K + lk8;
    const unsigned short* gB_h1 = Wthi + (size_t)nc1 * K + lk8;
    const unsigned short* gB_l0 = Wtlo + (size_t)nc0 * K + lk8;
    const unsigned short* gB_l1 = Wtlo + (size_t)nc1 * K + lk8;

    // --- A staging pointers: wave fills m-blocks 2w, 2w+1 (lane i -> ushort i*8) ---
    int ar0 = bm + 16 * (2 * w) + lm;     if (ar0 >= M) ar0 = M - 1;
    int ar1 = bm + 16 * (2 * w + 1) + lm; if (ar1 >= M) ar1 = M - 1;
    const unsigned short* gA_h0 = gAhi + (size_t)ar0 * K + lk8;
    const unsigned short* gA_h1 = gAhi + (size_t)ar1 * K + lk8;
    const unsigned short* gA_l0 = A_SPLIT ? gAlo + (size_t)ar0 * K + lk8 : nullptr;
    const unsigned short* gA_l1 = A_SPLIT ? gAlo + (size_t)ar1 * K + lk8 : nullptr;

    for (int k0 = 0; k0 < K; k0 += 32) {
        // ---- stage A ----
        lds_load16(gA_h0 + k0, &AhiL[(2 * w) * 512]);
        lds_load16(gA_h1 + k0, &AhiL[(2 * w + 1) * 512]);
        if (A_SPLIT) {
            lds_load16(gA_l0 + k0, &AloL[(2 * w) * 512]);
            lds_load16(gA_l1 + k0, &AloL[(2 * w + 1) * 512]);
        }
        // ---- stage B ----
        lds_load16(gB_h0 + k0, &BhiL[(2 * w) * 512]);
        lds_load16(gB_h1 + k0, &BhiL[(2 * w + 1) * 512]);
        lds_load16(gB_l0 + k0, &BloL[(2 * w) * 512]);
        lds_load16(gB_l1 + k0, &BloL[(2 * w + 1) * 512]);
        __syncthreads();

        // ---- fragments ----
        short8 ah[4], av[4], bh[4], bv[4];
#pragma unroll
        for (int i = 0; i < 4; ++i) {
            int ao = (wr * 4 + i) * 512 + lane * 8;
            int bo = (wc * 4 + i) * 512 + lane * 8;
            ah[i] = *(const short8*)&AhiL[ao];
            if (A_SPLIT) av[i] = *(const short8*)&AloL[ao];
            bh[i] = *(const short8*)&BhiL[bo];
            bv[i] = *(const short8*)&BloL[bo];
        }
#pragma unroll
        for (int i = 0; i < 4; ++i)
#pragma unroll
            for (int j = 0; j < 4; ++j) {
                acc[i][j] = __builtin_amdgcn_mfma_f32_16x16x32_bf16(ah[i], bh[j], acc[i][j], 0, 0, 0);
                if (A_SPLIT)
                    acc[i][j] = __builtin_amdgcn_mfma_f32_16x16x32_bf16(av[i], bh[j], acc[i][j], 0, 0, 0);
                acc[i][j] = __builtin_amdgcn_mfma_f32_16x16x32_bf16(ah[i], bv[j], acc[i][j], 0, 0, 0);
            }
        __syncthreads();
    }

    // ---- epilogue: C/D layout col=lane&15, row=(lane>>4)*4+r ; store bf16 ----
    const int orow_base = bm + wr * 64;
    const int ocol_base = bn + wc * 64 + lm;
    const int rq = (lane >> 4) * 4;
#pragma unroll
    for (int i = 0; i < 4; ++i) {
#pragma unroll
        for (int r = 0; r < 4; ++r) {
            int row = orow_base + i * 16 + rq + r;
            if (row >= M) continue;
            float s = inv_sqrt[row];
            size_t rb = (size_t)row * Ncol;
#pragma unroll
            for (int j = 0; j < 4; ++j)
                C[rb + ocol_base + j * 16] = f2bf(acc[i][j][r] * s);
        }
    }
}

// ---------------- fp32 vector GEMM for layer 3 (A given as hi/lo bf16) ----------------

__global__ __launch_bounds__(256) void gemm_scaled_hl_kernel(
        const unsigned short* __restrict__ Ahi, const unsigned short* __restrict__ Alo,
        const float* __restrict__ W,
        const float* __restrict__ inv_sqrt, float* __restrict__ C,
        int M, int K, int Ncol) {
    __shared__ float As[16][64];
    __shared__ float Ws[16][64];
    int tid = threadIdx.x;
    int tm = tid >> 4;
    int tn = tid & 15;
    int bm = blockIdx.x * 64;
    int bn = blockIdx.y * 64;

    float acc[4][4] = {};

    int lr = tid >> 2;
    int lc = (tid & 3) << 2;
    int wr = tid >> 4;
    int wc = (tid & 15) << 2;
    int arow = bm + lr;
    bool aok = arow < M;
    bool wok = (bn + wc) < Ncol;
    const unsigned short* AhiRow = Ahi + (size_t)arow * K + lc;
    const unsigned short* AloRow = Alo + (size_t)arow * K + lc;

    for (int k0 = 0; k0 < K; k0 += 16) {
        float4 av = make_float4(0.f, 0.f, 0.f, 0.f);
        if (aok) {
            ushort4 hv = *(const ushort4*)(AhiRow + k0);
            ushort4 lv = *(const ushort4*)(AloRow + k0);
            av.x = bf2f(hv.x) + bf2f(lv.x);
            av.y = bf2f(hv.y) + bf2f(lv.y);
            av.z = bf2f(hv.z) + bf2f(lv.z);
            av.w = bf2f(hv.w) + bf2f(lv.w);
        }
        As[lc + 0][lr] = av.x; As[lc + 1][lr] = av.y;
        As[lc + 2][lr] = av.z; As[lc + 3][lr] = av.w;

        float4 wv = make_float4(0.f, 0.f, 0.f, 0.f);
        if (wok) wv = *(const float4*)(W + (size_t)(k0 + wr) * Ncol + bn + wc);
        *(float4*)&Ws[wr][wc] = wv;
        __syncthreads();

#pragma unroll
        for (int k = 0; k < 16; ++k) {
            const float4 a4 = *(const float4*)&As[k][tm << 2];
            const float4 b4 = *(const float4*)&Ws[k][tn << 2];
            float a[4] = {a4.x, a4.y, a4.z, a4.w};
            float b[4] = {b4.x, b4.y, b4.z, b4.w};
#pragma unroll
            for (int i = 0; i < 4; ++i)
#pragma unroll
                for (int j = 0; j < 4; ++j)
                    acc[i][j] = fmaf(a[i], b[j], acc[i][j]);
        }
        __syncthreads();
    }

#pragma unroll
    for (int i = 0; i < 4; ++i) {
        int row = bm + (tm << 2) + i;
        if (row >= M) continue;
        float s = inv_sqrt[row];
        int col = bn + (tn << 2);
        if (col < Ncol) {
            float4 o = make_float4(acc[i][0] * s, acc[i][1] * s, acc[i][2] * s, acc[i][3] * s);
            *(float4*)&C[(size_t)row * Ncol + col] = o;
        }
    }
}

// ---------------- aggregation (H=256): one wave per node; g is bf16, acc fp32 ----------------
// Indices batch-loaded 64/wave + __shfl broadcast; gathers unrolled 8-wide.

__global__ __launch_bounds__(256) void agg_bn_hl_kernel(
        const unsigned short* __restrict__ g, const int* __restrict__ row_ptr,
        const int* __restrict__ srcs, const float* __restrict__ inv_sqrt,
        const float* __restrict__ bias, const float* __restrict__ gamma,
        const float* __restrict__ beta, const float* __restrict__ mean,
        const float* __restrict__ var,
        unsigned short* __restrict__ out_hi, unsigned short* __restrict__ out_lo, int n) {
    int node = (blockIdx.x << 2) + (threadIdx.x >> 6);
    int lane = threadIdx.x & 63;
    if (node >= n) return;
    const ushort4* gp = (const ushort4*)g;   // 64 ushort4 per 256-elem row
    float4 acc0 = make_float4(0.f, 0.f, 0.f, 0.f);
    float4 acc1 = make_float4(0.f, 0.f, 0.f, 0.f);
    accum_bf4(acc0, gp[(size_t)node * 64 + lane]);   // self-loop
    int beg = row_ptr[node];
    int cnt = row_ptr[node + 1] - beg;

    for (int base = 0; base < cnt; base += 64) {
        int m = cnt - base; if (m > 64) m = 64;
        int idx = (lane < m) ? srcs[beg + base + lane] : 0;
        int j = 0;
        for (; j + 8 <= m; j += 8) {
            int s0 = __shfl(idx, j + 0), s1 = __shfl(idx, j + 1);
            int s2 = __shfl(idx, j + 2), s3 = __shfl(idx, j + 3);
            int s4 = __shfl(idx, j + 4), s5 = __shfl(idx, j + 5);
            int s6 = __shfl(idx, j + 6), s7 = __shfl(idx, j + 7);
            ushort4 v0 = gp[(size_t)s0 * 64 + lane];
            ushort4 v1 = gp[(size_t)s1 * 64 + lane];
            ushort4 v2 = gp[(size_t)s2 * 64 + lane];
            ushort4 v3 = gp[(size_t)s3 * 64 + lane];
            ushort4 v4 = gp[(size_t)s4 * 64 + lane];
            ushort4 v5 = gp[(size_t)s5 * 64 + lane];
            ushort4 v6 = gp[(size_t)s6 * 64 + lane];
            ushort4 v7 = gp[(size_t)s7 * 64 + lane];
            accum_bf4(acc0, v0); accum_bf4(acc0, v1);
            accum_bf4(acc0, v2); accum_bf4(acc0, v3);
            accum_bf4(acc1, v4); accum_bf4(acc1, v5);
            accum_bf4(acc1, v6); accum_bf4(acc1, v7);
        }
        for (; j < m; ++j) {
            int s = __shfl(idx, j);
            accum_bf4(acc0, gp[(size_t)s * 64 + lane]);
        }
    }
    float4 acc = f4add(acc0, acc1);

    float inv = inv_sqrt[node];
    float4 b4  = ((const float4*)bias)[lane];
    float4 ga4 = ((const float4*)gamma)[lane];
    float4 be4 = ((const float4*)beta)[lane];
    float4 m4  = ((const float4*)mean)[lane];
    float4 v4  = ((const float4*)var)[lane];
    float4 o;
    o.x = fmaxf((acc.x * inv + b4.x - m4.x) * (ga4.x * rsqrtf(v4.x + EPS)) + be4.x, 0.f);
    o.y = fmaxf((acc.y * inv + b4.y - m4.y) * (ga4.y * rsqrtf(v4.y + EPS)) + be4.y, 0.f);
    o.z = fmaxf((acc.z * inv + b4.z - m4.z) * (ga4.z * rsqrtf(v4.z + EPS)) + be4.z, 0.f);
    o.w = fmaxf((acc.w * inv + b4.w - m4.w) * (ga4.w * rsqrtf(v4.w + EPS)) + be4.w, 0.f);
    ushort4 oh, ol;
    oh.x = f2bf(o.x); ol.x = f2bf(o.x - bf2f(oh.x));
    oh.y = f2bf(o.y); ol.y = f2bf(o.y - bf2f(oh.y));
    oh.z = f2bf(o.z); ol.z = f2bf(o.z - bf2f(oh.z));
    oh.w = f2bf(o.w); ol.w = f2bf(o.w - bf2f(oh.w));
    ((ushort4*)out_hi)[(size_t)node * 64 + lane] = oh;
    ((ushort4*)out_lo)[(size_t)node * 64 + lane] = ol;
}

// ---------------- final aggregation (C=40): fp32; all 64 lanes stay alive for shfl ----------------

__global__ __launch_bounds__(256) void agg_final_kernel(
        const float* __restrict__ g, const int* __restrict__ row_ptr,
        const int* __restrict__ srcs, const float* __restrict__ inv_sqrt,
        const float* __restrict__ bias, float* __restrict__ out, int n) {
    int node = (blockIdx.x << 2) + (threadIdx.x >> 6);
    int lane = threadIdx.x & 63;
    if (node >= n) return;
    int flane = (lane < CLS) ? lane : 0;       // clamped gather lane; store masked below
    float acc0 = g[(size_t)node * CLS + flane];
    float acc1 = 0.f;
    int beg = row_ptr[node];
    int cnt = row_ptr[node + 1] - beg;

    for (int base = 0; base < cnt; base += 64) {
        int m = cnt - base; if (m > 64) m = 64;
        int idx = (lane < m) ? srcs[beg + base + lane] : 0;
        int j = 0;
        for (; j + 8 <= m; j += 8) {
            int s0 = __shfl(idx, j + 0), s1 = __shfl(idx, j + 1);
            int s2 = __shfl(idx, j + 2), s3 = __shfl(idx, j + 3);
            int s4 = __shfl(idx, j + 4), s5 = __shfl(idx, j + 5);
            int s6 = __shfl(idx, j + 6), s7 = __shfl(idx, j + 7);
            float v0 = g[(size_t)s0 * CLS + flane];
            float v1 = g[(size_t)s1 * CLS + flane];
            float v2 = g[(size_t)s2 * CLS + flane];
            float v3 = g[(size_t)s3 * CLS + flane];
            float v4 = g[(size_t)s4 * CLS + flane];
            float v5 = g[(size_t)s5 * CLS + flane];
            float v6 = g[(size_t)s6 * CLS + flane];
            float v7 = g[(size_t)s7 * CLS + flane];
            acc0 += (v0 + v1) + (v2 + v3);
            acc1 += (v4 + v5) + (v6 + v7);
        }
        for (; j < m; ++j) {
            int s = __shfl(idx, j);
            acc0 += g[(size_t)s * CLS + flane];
        }
    }
    if (lane < CLS)
        out[(size_t)node * CLS + lane] = (acc0 + acc1) * inv_sqrt[node] + bias[lane];
}

// ---------------- launch ----------------

extern "C" void kernel_launch(void* const* d_in, const int* in_sizes, int n_in,
                              void* d_out, int out_size, void* d_ws, size_t ws_size,
                              hipStream_t stream) {
    const float* x     = (const float*)d_in[0];
    const int*   edges = (const int*)d_in[1];
    const float* W1    = (const float*)d_in[2];
    const float* b1    = (const float*)d_in[3];
    const float* W2    = (const float*)d_in[4];
    const float* b2    = (const float*)d_in[5];
    const float* W3    = (const float*)d_in[6];
    const float* b3    = (const float*)d_in[7];
    const float* gamma = (const float*)d_in[8];
    const float* beta  = (const float*)d_in[9];
    const float* mean  = (const float*)d_in[10];
    const float* var   = (const float*)d_in[11];

    const int N = in_sizes[0] / FEAT;   // 50000
    const int E = in_sizes[1] / 2;      // 800000
    const int* src = edges;
    const int* dst = edges + E;

    char* ws = (char*)d_ws;
    auto alloc = [&](size_t bytes) -> char* {
        char* p = ws;
        ws += (bytes + 255) & ~(size_t)255;
        return p;
    };
    int*   counts     = (int*)  alloc((size_t)N * 4);
    int*   fillpos    = (int*)  alloc((size_t)N * 4);
    int*   row_ptr    = (int*)  alloc((size_t)(N + 1) * 4);
    int*   blocksums  = (int*)  alloc(256 * 4);
    int*   blockoffs  = (int*)  alloc(256 * 4);
    float* inv_sqrt   = (float*)alloc((size_t)N * 4);
    int*   src_sorted = (int*)  alloc((size_t)E * 4);
    unsigned short* w1hi = (unsigned short*)alloc((size_t)FEAT * HID * 2);
    unsigned short* w1lo = (unsigned short*)alloc((size_t)FEAT * HID * 2);
    unsigned short* w2hi = (unsigned short*)alloc((size_t)HID * HID * 2);
    unsigned short* w2lo = (unsigned short*)alloc((size_t)HID * HID * 2);
    // g: bf16 for layers 1-2 (25.6 MB); reused as fp32 N*CLS (8 MB) for layer 3
    unsigned short* g    = (unsigned short*)alloc((size_t)N * HID * 2);
    unsigned short* h_hi = (unsigned short*)alloc((size_t)N * HID * 2); // 25.6 MB
    unsigned short* h_lo = (unsigned short*)alloc((size_t)N * HID * 2); // 25.6 MB
    // xbf (N*FEAT bf16 = 51.2 MB) aliases h_hi+h_lo: dead once GEMM1 completes,
    // and agg1 (which writes h_hi/h_lo) runs strictly after GEMM1 on the stream.
    unsigned short* xbf  = h_hi;

    int nb = (N + 255) / 256;
    int eb = (E + 255) / 256;

    zero_kernel<<<nb, 256, 0, stream>>>(counts, fillpos, N);
    hist_kernel<<<eb, 256, 0, stream>>>(dst, counts, E);
    scan_block_kernel<<<nb, 256, 0, stream>>>(counts, row_ptr, blocksums, N);
    scan_sums_kernel<<<1, 256, 0, stream>>>(blocksums, blockoffs, nb);
    finalize_rowptr_kernel<<<nb, 256, 0, stream>>>(row_ptr, blockoffs, counts, inv_sqrt, N, E);
    fill_kernel<<<eb, 256, 0, stream>>>(src, dst, row_ptr, fillpos, src_sorted, E);

    cvt_w_kernel<<<(FEAT * HID + 255) / 256, 256, 0, stream>>>(W1, w1hi, w1lo, FEAT, HID);
    cvt_w_kernel<<<(HID * HID + 255) / 256, 256, 0, stream>>>(W2, w2hi, w2lo, HID, HID);
    int total8 = N * FEAT / 8;
    cvt_x_kernel<<<(total8 + 255) / 256, 256, 0, stream>>>(x, xbf, total8);

    dim3 mfma_grid((N + 127) / 128, HID / 128);
    dim3 gemm3_grid((N + 63) / 64, 1);
    dim3 agg_grid((N + 3) / 4);

    // layer 1: A = bf16(x) single (2 MFMAs); output g bf16
    gemm_mfma_kernel<false><<<mfma_grid, 256, 0, stream>>>(
        xbf, nullptr, w1hi, w1lo, inv_sqrt, g, N, FEAT, HID);
    agg_bn_hl_kernel<<<agg_grid, 256, 0, stream>>>(g, row_ptr, src_sorted, inv_sqrt,
                                                   b1, gamma, beta, mean, var, h_hi, h_lo, N);
    // layer 2: A = h1 (pre-split hi/lo, 3 MFMAs); output g bf16
    gemm_mfma_kernel<true><<<mfma_grid, 256, 0, stream>>>(
        h_hi, h_lo, w2hi, w2lo, inv_sqrt, g, N, HID, HID);
    agg_bn_hl_kernel<<<agg_grid, 256, 0, stream>>>(g, row_ptr, src_sorted, inv_sqrt,
                                                   b2, gamma, beta, mean, var, h_hi, h_lo, N);
    // layer 3: fp32 vector GEMM reading hi/lo; fp32 g3 (reuses g buffer); fp32 final agg
    float* g3 = (float*)g;
    gemm_scaled_hl_kernel<<<gemm3_grid, 256, 0, stream>>>(h_hi, h_lo, W3, inv_sqrt, g3, N, HID, CLS);
    agg_final_kernel<<<agg_grid, 256, 0, stream>>>(g3, row_ptr, src_sorted, inv_sqrt,
                                                   b3, (float*)d_out, N);
}

// Round 7
// 558.198 us; speedup vs baseline: 1.0112x; 1.0112x over previous
//
#include <hip/hip_runtime.h>
#include <cstdint>
#include <cstddef>

#define FEAT 512
#define HID 256
#define CLS 40
#define EPS 1e-5f

typedef __attribute__((ext_vector_type(8))) short short8;
typedef __attribute__((ext_vector_type(4))) float f32x4v;

// ---------------- helpers ----------------

__device__ __forceinline__ unsigned short f2bf(float f) {
    union { float f; unsigned u; } v; v.f = f;
    unsigned r = v.u + 0x7FFF + ((v.u >> 16) & 1);   // round-to-nearest-even
    return (unsigned short)(r >> 16);
}
__device__ __forceinline__ float bf2f(unsigned short h) {
    union { unsigned u; float f; } v; v.u = ((unsigned)h) << 16;
    return v.f;
}

typedef const __attribute__((address_space(1))) unsigned int* gas_ptr;
typedef __attribute__((address_space(3))) unsigned int* las_ptr;
__device__ __forceinline__ void lds_load16(const void* g, void* l) {
    __builtin_amdgcn_global_load_lds((gas_ptr)g, (las_ptr)l, 16, 0, 0);
}

__device__ __forceinline__ float4 f4add(float4 a, float4 b) {
    return make_float4(a.x + b.x, a.y + b.y, a.z + b.z, a.w + b.w);
}

// accumulate a bf16x4 row fragment into a float4
__device__ __forceinline__ void accum_bf4(float4& a, ushort4 v) {
    a.x += bf2f(v.x); a.y += bf2f(v.y); a.z += bf2f(v.z); a.w += bf2f(v.w);
}

// ---------------- preprocessing: degree, CSR build ----------------

__global__ void zero_kernel(int* counts, int* fillpos, int n) {
    int i = blockIdx.x * 256 + threadIdx.x;
    if (i < n) { counts[i] = 0; fillpos[i] = 0; }
}

__global__ void hist_kernel(const int* __restrict__ dst, int* __restrict__ counts, int E) {
    int e = blockIdx.x * 256 + threadIdx.x;
    if (e < E) atomicAdd(&counts[dst[e]], 1);
}

__global__ void scan_block_kernel(const int* __restrict__ counts, int* __restrict__ row_ptr,
                                  int* __restrict__ blocksums, int n) {
    __shared__ int s[256];
    int tid = threadIdx.x;
    int i = blockIdx.x * 256 + tid;
    int v = (i < n) ? counts[i] : 0;
    s[tid] = v; __syncthreads();
    for (int off = 1; off < 256; off <<= 1) {
        int t = (tid >= off) ? s[tid - off] : 0;
        __syncthreads();
        s[tid] += t;
        __syncthreads();
    }
    if (i < n) row_ptr[i] = s[tid] - v;
    if (tid == 255) blocksums[blockIdx.x] = s[255];
}

__global__ void scan_sums_kernel(const int* __restrict__ blocksums, int* __restrict__ blockoffs, int nb) {
    __shared__ int s[256];
    int tid = threadIdx.x;
    int v = (tid < nb) ? blocksums[tid] : 0;
    s[tid] = v; __syncthreads();
    for (int off = 1; off < 256; off <<= 1) {
        int t = (tid >= off) ? s[tid - off] : 0;
        __syncthreads();
        s[tid] += t;
        __syncthreads();
    }
    blockoffs[tid] = s[tid] - v;
}

__global__ void finalize_rowptr_kernel(int* __restrict__ row_ptr, const int* __restrict__ blockoffs,
                                       const int* __restrict__ counts, float* __restrict__ inv_sqrt,
                                       int n, int E) {
    int i = blockIdx.x * 256 + threadIdx.x;
    if (i < n) {
        row_ptr[i] += blockoffs[i >> 8];
        inv_sqrt[i] = rsqrtf((float)(counts[i] + 1));
    }
    if (i == 0) row_ptr[n] = E;
}

__global__ void fill_kernel(const int* __restrict__ src, const int* __restrict__ dst,
                            const int* __restrict__ row_ptr, int* __restrict__ fillpos,
                            int* __restrict__ src_sorted, int E) {
    int e = blockIdx.x * 256 + threadIdx.x;
    if (e < E) {
        int d = dst[e];
        int pos = row_ptr[d] + atomicAdd(&fillpos[d], 1);
        src_sorted[pos] = src[e];
    }
}

// ---------------- weight split+transpose: W[K][Ncol] fp32 -> Wt_hi/lo [Ncol][K] bf16 ----------------

__global__ void cvt_w_kernel(const float* __restrict__ W, unsigned short* __restrict__ hi,
                             unsigned short* __restrict__ lo, int K, int Ncol) {
    int idx = blockIdx.x * 256 + threadIdx.x;
    if (idx >= K * Ncol) return;
    int k = idx / Ncol, n = idx % Ncol;
    float f = W[idx];
    unsigned short h = f2bf(f);
    hi[(size_t)n * K + k] = h;
    lo[(size_t)n * K + k] = f2bf(f - bf2f(h));
}

// ---------------- x fp32 -> bf16 (memory-bound pass; each thread converts 8) ----------------

__global__ __launch_bounds__(256) void cvt_x_kernel(const float* __restrict__ x,
                                                    unsigned short* __restrict__ out, int total8) {
    int i = blockIdx.x * 256 + threadIdx.x;
    if (i >= total8) return;
    const float4* xp = (const float4*)x;
    float4 a = xp[2 * i], b = xp[2 * i + 1];
    float f[8] = {a.x, a.y, a.z, a.w, b.x, b.y, b.z, b.w};
    short8 h;
#pragma unroll
    for (int j = 0; j < 8; ++j) h[j] = (short)f2bf(f[j]);
    ((short8*)out)[i] = h;
}

// ---------------- split-bf16 MFMA GEMM ----------------
// C[row][col] = bf16( (A @ W)[row][col] * inv_sqrt[row] ), W = Whi+Wlo.
// A_SPLIT=true : A = Ahi+Alo (3 MFMAs/pair).   A_SPLIT=false: A = single bf16 (2 MFMAs/pair).
// 128x128 tile, BK template (32 or 64), 4 waves, each wave 64x64 = 4x4 frags of 16x16x32.
// LDS fragment-linear per 16-row m-block (BLK=16*BK ushorts/block):
//   elem(m^,k_local) at BLK*b + 8*m^ + 128*(k_local>>3 within 32-k chunk) + 512*(k_local>>5) + (k_local&7)
//   => each 32-k chunk is one wave-load (64 lanes x 16B), frag reads are lane*16B ds_read_b128.
// Wt is [n][k] so B-fragments are contiguous 16B runs too. All staging via global_load_lds w=16.
// BK=64 halves barrier count (the vmcnt(0) drain at __syncthreads is the limiter at ~3 blocks/CU).

template<bool A_SPLIT, int BK>
__global__ __launch_bounds__(256) void gemm_mfma_kernel(
        const unsigned short* __restrict__ gAhi, const unsigned short* __restrict__ gAlo,
        const unsigned short* __restrict__ Wthi, const unsigned short* __restrict__ Wtlo,
        const float* __restrict__ inv_sqrt, unsigned short* __restrict__ C,
        int M, int K, int Ncol) {
    constexpr int BLK = 16 * BK;               // ushorts per 16-row block
    __shared__ unsigned short AhiL[128 * BK];
    __shared__ unsigned short AloL[A_SPLIT ? 128 * BK : 4];
    __shared__ unsigned short BhiL[128 * BK], BloL[128 * BK];
    const int tid  = threadIdx.x;
    const int lane = tid & 63;
    const int w    = tid >> 6;        // wave 0..3
    const int wr   = w >> 1, wc = w & 1;
    const int lm   = lane & 15;
    const int lk8  = (lane >> 4) * 8;
    const int bm   = blockIdx.x * 128;
    const int bn   = blockIdx.y * 128;

    f32x4v acc[4][4] = {};

    // --- B staging pointers (wave fills n-blocks 2w, 2w+1, hi+lo) ---
    int nc0 = bn + 16 * (2 * w) + lm;
    int nc1 = bn + 16 * (2 * w + 1) + lm;
    const unsigned short* gB_h0 = Wthi + (size_t)nc0 * K + lk8;
    const unsigned short* gB_h1 = Wthi + (size_t)nc1 * K + lk8;
    const unsigned short* gB_l0 = Wtlo + (size_t)nc0 * K + lk8;
    const unsigned short* gB_l1 = Wtlo + (size_t)nc1 * K + lk8;

    // --- A staging pointers: wave fills m-blocks 2w, 2w+1 (lane i -> ushort i*8) ---
    int ar0 = bm + 16 * (2 * w) + lm;     if (ar0 >= M) ar0 = M - 1;
    int ar1 = bm + 16 * (2 * w + 1) + lm; if (ar1 >= M) ar1 = M - 1;
    const unsigned short* gA_h0 = gAhi + (size_t)ar0 * K + lk8;
    const unsigned short* gA_h1 = gAhi + (size_t)ar1 * K + lk8;
    const unsigned short* gA_l0 = A_SPLIT ? gAlo + (size_t)ar0 * K + lk8 : nullptr;
    const unsigned short* gA_l1 = A_SPLIT ? gAlo + (size_t)ar1 * K + lk8 : nullptr;

    for (int k0 = 0; k0 < K; k0 += BK) {
        // ---- stage A+B: per 32-k chunk kk, one wave-load per (block, operand) ----
#pragma unroll
        for (int kk = 0; kk < BK / 32; ++kk) {
            const int kg = k0 + 32 * kk;
            const int lo = kk * 512;           // ushort offset of 32-k chunk within block
            lds_load16(gA_h0 + kg, &AhiL[(2 * w) * BLK + lo]);
            lds_load16(gA_h1 + kg, &AhiL[(2 * w + 1) * BLK + lo]);
            if (A_SPLIT) {
                lds_load16(gA_l0 + kg, &AloL[(2 * w) * BLK + lo]);
                lds_load16(gA_l1 + kg, &AloL[(2 * w + 1) * BLK + lo]);
            }
            lds_load16(gB_h0 + kg, &BhiL[(2 * w) * BLK + lo]);
            lds_load16(gB_h1 + kg, &BhiL[(2 * w + 1) * BLK + lo]);
            lds_load16(gB_l0 + kg, &BloL[(2 * w) * BLK + lo]);
            lds_load16(gB_l1 + kg, &BloL[(2 * w + 1) * BLK + lo]);
        }
        __syncthreads();

        // ---- compute: one 32-k half at a time ----
#pragma unroll
        for (int half = 0; half < BK / 32; ++half) {
            const int ho = half * 512;
            short8 ah[4], av[4], bh[4], bv[4];
#pragma unroll
            for (int i = 0; i < 4; ++i) {
                int ao = (wr * 4 + i) * BLK + ho + lane * 8;
                int bo = (wc * 4 + i) * BLK + ho + lane * 8;
                ah[i] = *(const short8*)&AhiL[ao];
                if (A_SPLIT) av[i] = *(const short8*)&AloL[ao];
                bh[i] = *(const short8*)&BhiL[bo];
                bv[i] = *(const short8*)&BloL[bo];
            }
#pragma unroll
            for (int i = 0; i < 4; ++i)
#pragma unroll
                for (int j = 0; j < 4; ++j) {
                    acc[i][j] = __builtin_amdgcn_mfma_f32_16x16x32_bf16(ah[i], bh[j], acc[i][j], 0, 0, 0);
                    if (A_SPLIT)
                        acc[i][j] = __builtin_amdgcn_mfma_f32_16x16x32_bf16(av[i], bh[j], acc[i][j], 0, 0, 0);
                    acc[i][j] = __builtin_amdgcn_mfma_f32_16x16x32_bf16(ah[i], bv[j], acc[i][j], 0, 0, 0);
                }
        }
        __syncthreads();
    }

    // ---- epilogue: C/D layout col=lane&15, row=(lane>>4)*4+r ; store bf16 ----
    const int orow_base = bm + wr * 64;
    const int ocol_base = bn + wc * 64 + lm;
    const int rq = (lane >> 4) * 4;
#pragma unroll
    for (int i = 0; i < 4; ++i) {
#pragma unroll
        for (int r = 0; r < 4; ++r) {
            int row = orow_base + i * 16 + rq + r;
            if (row >= M) continue;
            float s = inv_sqrt[row];
            size_t rb = (size_t)row * Ncol;
#pragma unroll
            for (int j = 0; j < 4; ++j)
                C[rb + ocol_base + j * 16] = f2bf(acc[i][j][r] * s);
        }
    }
}

// ---------------- fp32 vector GEMM for layer 3 (A given as hi/lo bf16) ----------------

__global__ __launch_bounds__(256) void gemm_scaled_hl_kernel(
        const unsigned short* __restrict__ Ahi, const unsigned short* __restrict__ Alo,
        const float* __restrict__ W,
        const float* __restrict__ inv_sqrt, float* __restrict__ C,
        int M, int K, int Ncol) {
    __shared__ float As[16][64];
    __shared__ float Ws[16][64];
    int tid = threadIdx.x;
    int tm = tid >> 4;
    int tn = tid & 15;
    int bm = blockIdx.x * 64;
    int bn = blockIdx.y * 64;

    float acc[4][4] = {};

    int lr = tid >> 2;
    int lc = (tid & 3) << 2;
    int wr = tid >> 4;
    int wc = (tid & 15) << 2;
    int arow = bm + lr;
    bool aok = arow < M;
    bool wok = (bn + wc) < Ncol;
    const unsigned short* AhiRow = Ahi + (size_t)arow * K + lc;
    const unsigned short* AloRow = Alo + (size_t)arow * K + lc;

    for (int k0 = 0; k0 < K; k0 += 16) {
        float4 av = make_float4(0.f, 0.f, 0.f, 0.f);
        if (aok) {
            ushort4 hv = *(const ushort4*)(AhiRow + k0);
            ushort4 lv = *(const ushort4*)(AloRow + k0);
            av.x = bf2f(hv.x) + bf2f(lv.x);
            av.y = bf2f(hv.y) + bf2f(lv.y);
            av.z = bf2f(hv.z) + bf2f(lv.z);
            av.w = bf2f(hv.w) + bf2f(lv.w);
        }
        As[lc + 0][lr] = av.x; As[lc + 1][lr] = av.y;
        As[lc + 2][lr] = av.z; As[lc + 3][lr] = av.w;

        float4 wv = make_float4(0.f, 0.f, 0.f, 0.f);
        if (wok) wv = *(const float4*)(W + (size_t)(k0 + wr) * Ncol + bn + wc);
        *(float4*)&Ws[wr][wc] = wv;
        __syncthreads();

#pragma unroll
        for (int k = 0; k < 16; ++k) {
            const float4 a4 = *(const float4*)&As[k][tm << 2];
            const float4 b4 = *(const float4*)&Ws[k][tn << 2];
            float a[4] = {a4.x, a4.y, a4.z, a4.w};
            float b[4] = {b4.x, b4.y, b4.z, b4.w};
#pragma unroll
            for (int i = 0; i < 4; ++i)
#pragma unroll
                for (int j = 0; j < 4; ++j)
                    acc[i][j] = fmaf(a[i], b[j], acc[i][j]);
        }
        __syncthreads();
    }

#pragma unroll
    for (int i = 0; i < 4; ++i) {
        int row = bm + (tm << 2) + i;
        if (row >= M) continue;
        float s = inv_sqrt[row];
        int col = bn + (tn << 2);
        if (col < Ncol) {
            float4 o = make_float4(acc[i][0] * s, acc[i][1] * s, acc[i][2] * s, acc[i][3] * s);
            *(float4*)&C[(size_t)row * Ncol + col] = o;
        }
    }
}

// ---------------- aggregation (H=256): one wave per node; g is bf16, acc fp32 ----------------
// Indices batch-loaded 64/wave + __shfl broadcast; gathers unrolled 8-wide.

__global__ __launch_bounds__(256) void agg_bn_hl_kernel(
        const unsigned short* __restrict__ g, const int* __restrict__ row_ptr,
        const int* __restrict__ srcs, const float* __restrict__ inv_sqrt,
        const float* __restrict__ bias, const float* __restrict__ gamma,
        const float* __restrict__ beta, const float* __restrict__ mean,
        const float* __restrict__ var,
        unsigned short* __restrict__ out_hi, unsigned short* __restrict__ out_lo, int n) {
    int node = (blockIdx.x << 2) + (threadIdx.x >> 6);
    int lane = threadIdx.x & 63;
    if (node >= n) return;
    const ushort4* gp = (const ushort4*)g;   // 64 ushort4 per 256-elem row
    float4 acc0 = make_float4(0.f, 0.f, 0.f, 0.f);
    float4 acc1 = make_float4(0.f, 0.f, 0.f, 0.f);
    accum_bf4(acc0, gp[(size_t)node * 64 + lane]);   // self-loop
    int beg = row_ptr[node];
    int cnt = row_ptr[node + 1] - beg;

    for (int base = 0; base < cnt; base += 64) {
        int m = cnt - base; if (m > 64) m = 64;
        int idx = (lane < m) ? srcs[beg + base + lane] : 0;
        int j = 0;
        for (; j + 8 <= m; j += 8) {
            int s0 = __shfl(idx, j + 0), s1 = __shfl(idx, j + 1);
            int s2 = __shfl(idx, j + 2), s3 = __shfl(idx, j + 3);
            int s4 = __shfl(idx, j + 4), s5 = __shfl(idx, j + 5);
            int s6 = __shfl(idx, j + 6), s7 = __shfl(idx, j + 7);
            ushort4 v0 = gp[(size_t)s0 * 64 + lane];
            ushort4 v1 = gp[(size_t)s1 * 64 + lane];
            ushort4 v2 = gp[(size_t)s2 * 64 + lane];
            ushort4 v3 = gp[(size_t)s3 * 64 + lane];
            ushort4 v4 = gp[(size_t)s4 * 64 + lane];
            ushort4 v5 = gp[(size_t)s5 * 64 + lane];
            ushort4 v6 = gp[(size_t)s6 * 64 + lane];
            ushort4 v7 = gp[(size_t)s7 * 64 + lane];
            accum_bf4(acc0, v0); accum_bf4(acc0, v1);
            accum_bf4(acc0, v2); accum_bf4(acc0, v3);
            accum_bf4(acc1, v4); accum_bf4(acc1, v5);
            accum_bf4(acc1, v6); accum_bf4(acc1, v7);
        }
        for (; j < m; ++j) {
            int s = __shfl(idx, j);
            accum_bf4(acc0, gp[(size_t)s * 64 + lane]);
        }
    }
    float4 acc = f4add(acc0, acc1);

    float inv = inv_sqrt[node];
    float4 b4  = ((const float4*)bias)[lane];
    float4 ga4 = ((const float4*)gamma)[lane];
    float4 be4 = ((const float4*)beta)[lane];
    float4 m4  = ((const float4*)mean)[lane];
    float4 v4  = ((const float4*)var)[lane];
    float4 o;
    o.x = fmaxf((acc.x * inv + b4.x - m4.x) * (ga4.x * rsqrtf(v4.x + EPS)) + be4.x, 0.f);
    o.y = fmaxf((acc.y * inv + b4.y - m4.y) * (ga4.y * rsqrtf(v4.y + EPS)) + be4.y, 0.f);
    o.z = fmaxf((acc.z * inv + b4.z - m4.z) * (ga4.z * rsqrtf(v4.z + EPS)) + be4.z, 0.f);
    o.w = fmaxf((acc.w * inv + b4.w - m4.w) * (ga4.w * rsqrtf(v4.w + EPS)) + be4.w, 0.f);
    ushort4 oh, ol;
    oh.x = f2bf(o.x); ol.x = f2bf(o.x - bf2f(oh.x));
    oh.y = f2bf(o.y); ol.y = f2bf(o.y - bf2f(oh.y));
    oh.z = f2bf(o.z); ol.z = f2bf(o.z - bf2f(oh.z));
    oh.w = f2bf(o.w); ol.w = f2bf(o.w - bf2f(oh.w));
    ((ushort4*)out_hi)[(size_t)node * 64 + lane] = oh;
    ((ushort4*)out_lo)[(size_t)node * 64 + lane] = ol;
}

// ---------------- final aggregation (C=40): fp32; all 64 lanes stay alive for shfl ----------------

__global__ __launch_bounds__(256) void agg_final_kernel(
        const float* __restrict__ g, const int* __restrict__ row_ptr,
        const int* __restrict__ srcs, const float* __restrict__ inv_sqrt,
        const float* __restrict__ bias, float* __restrict__ out, int n) {
    int node = (blockIdx.x << 2) + (threadIdx.x >> 6);
    int lane = threadIdx.x & 63;
    if (node >= n) return;
    int flane = (lane < CLS) ? lane : 0;       // clamped gather lane; store masked below
    float acc0 = g[(size_t)node * CLS + flane];
    float acc1 = 0.f;
    int beg = row_ptr[node];
    int cnt = row_ptr[node + 1] - beg;

    for (int base = 0; base < cnt; base += 64) {
        int m = cnt - base; if (m > 64) m = 64;
        int idx = (lane < m) ? srcs[beg + base + lane] : 0;
        int j = 0;
        for (; j + 8 <= m; j += 8) {
            int s0 = __shfl(idx, j + 0), s1 = __shfl(idx, j + 1);
            int s2 = __shfl(idx, j + 2), s3 = __shfl(idx, j + 3);
            int s4 = __shfl(idx, j + 4), s5 = __shfl(idx, j + 5);
            int s6 = __shfl(idx, j + 6), s7 = __shfl(idx, j + 7);
            float v0 = g[(size_t)s0 * CLS + flane];
            float v1 = g[(size_t)s1 * CLS + flane];
            float v2 = g[(size_t)s2 * CLS + flane];
            float v3 = g[(size_t)s3 * CLS + flane];
            float v4 = g[(size_t)s4 * CLS + flane];
            float v5 = g[(size_t)s5 * CLS + flane];
            float v6 = g[(size_t)s6 * CLS + flane];
            float v7 = g[(size_t)s7 * CLS + flane];
            acc0 += (v0 + v1) + (v2 + v3);
            acc1 += (v4 + v5) + (v6 + v7);
        }
        for (; j < m; ++j) {
            int s = __shfl(idx, j);
            acc0 += g[(size_t)s * CLS + flane];
        }
    }
    if (lane < CLS)
        out[(size_t)node * CLS + lane] = (acc0 + acc1) * inv_sqrt[node] + bias[lane];
}

// ---------------- launch ----------------

extern "C" void kernel_launch(void* const* d_in, const int* in_sizes, int n_in,
                              void* d_out, int out_size, void* d_ws, size_t ws_size,
                              hipStream_t stream) {
    const float* x     = (const float*)d_in[0];
    const int*   edges = (const int*)d_in[1];
    const float* W1    = (const float*)d_in[2];
    const float* b1    = (const float*)d_in[3];
    const float* W2    = (const float*)d_in[4];
    const float* b2    = (const float*)d_in[5];
    const float* W3    = (const float*)d_in[6];
    const float* b3    = (const float*)d_in[7];
    const float* gamma = (const float*)d_in[8];
    const float* beta  = (const float*)d_in[9];
    const float* mean  = (const float*)d_in[10];
    const float* var   = (const float*)d_in[11];

    const int N = in_sizes[0] / FEAT;   // 50000
    const int E = in_sizes[1] / 2;      // 800000
    const int* src = edges;
    const int* dst = edges + E;

    char* ws = (char*)d_ws;
    auto alloc = [&](size_t bytes) -> char* {
        char* p = ws;
        ws += (bytes + 255) & ~(size_t)255;
        return p;
    };
    int*   counts     = (int*)  alloc((size_t)N * 4);
    int*   fillpos    = (int*)  alloc((size_t)N * 4);
    int*   row_ptr    = (int*)  alloc((size_t)(N + 1) * 4);
    int*   blocksums  = (int*)  alloc(256 * 4);
    int*   blockoffs  = (int*)  alloc(256 * 4);
    float* inv_sqrt   = (float*)alloc((size_t)N * 4);
    int*   src_sorted = (int*)  alloc((size_t)E * 4);
    unsigned short* w1hi = (unsigned short*)alloc((size_t)FEAT * HID * 2);
    unsigned short* w1lo = (unsigned short*)alloc((size_t)FEAT * HID * 2);
    unsigned short* w2hi = (unsigned short*)alloc((size_t)HID * HID * 2);
    unsigned short* w2lo = (unsigned short*)alloc((size_t)HID * HID * 2);
    // g: bf16 for layers 1-2 (25.6 MB); reused as fp32 N*CLS (8 MB) for layer 3
    unsigned short* g    = (unsigned short*)alloc((size_t)N * HID * 2);
    unsigned short* h_hi = (unsigned short*)alloc((size_t)N * HID * 2); // 25.6 MB
    unsigned short* h_lo = (unsigned short*)alloc((size_t)N * HID * 2); // 25.6 MB
    // xbf (N*FEAT bf16 = 51.2 MB) aliases h_hi+h_lo: dead once GEMM1 completes,
    // and agg1 (which writes h_hi/h_lo) runs strictly after GEMM1 on the stream.
    unsigned short* xbf  = h_hi;

    int nb = (N + 255) / 256;
    int eb = (E + 255) / 256;

    zero_kernel<<<nb, 256, 0, stream>>>(counts, fillpos, N);
    hist_kernel<<<eb, 256, 0, stream>>>(dst, counts, E);
    scan_block_kernel<<<nb, 256, 0, stream>>>(counts, row_ptr, blocksums, N);
    scan_sums_kernel<<<1, 256, 0, stream>>>(blocksums, blockoffs, nb);
    finalize_rowptr_kernel<<<nb, 256, 0, stream>>>(row_ptr, blockoffs, counts, inv_sqrt, N, E);
    fill_kernel<<<eb, 256, 0, stream>>>(src, dst, row_ptr, fillpos, src_sorted, E);

    cvt_w_kernel<<<(FEAT * HID + 255) / 256, 256, 0, stream>>>(W1, w1hi, w1lo, FEAT, HID);
    cvt_w_kernel<<<(HID * HID + 255) / 256, 256, 0, stream>>>(W2, w2hi, w2lo, HID, HID);
    int total8 = N * FEAT / 8;
    cvt_x_kernel<<<(total8 + 255) / 256, 256, 0, stream>>>(x, xbf, total8);

    dim3 mfma_grid((N + 127) / 128, HID / 128);
    dim3 gemm3_grid((N + 63) / 64, 1);
    dim3 agg_grid((N + 3) / 4);

    // layer 1: A = bf16(x) single (2 MFMAs), BK=64 (8 barriers); output g bf16
    gemm_mfma_kernel<false, 64><<<mfma_grid, 256, 0, stream>>>(
        xbf, nullptr, w1hi, w1lo, inv_sqrt, g, N, FEAT, HID);
    agg_bn_hl_kernel<<<agg_grid, 256, 0, stream>>>(g, row_ptr, src_sorted, inv_sqrt,
                                                   b1, gamma, beta, mean, var, h_hi, h_lo, N);
    // layer 2: A = h1 (pre-split hi/lo, 3 MFMAs), BK=32; output g bf16
    gemm_mfma_kernel<true, 32><<<mfma_grid, 256, 0, stream>>>(
        h_hi, h_lo, w2hi, w2lo, inv_sqrt, g, N, HID, HID);
    agg_bn_hl_kernel<<<agg_grid, 256, 0, stream>>>(g, row_ptr, src_sorted, inv_sqrt,
                                                   b2, gamma, beta, mean, var, h_hi, h_lo, N);
    // layer 3: fp32 vector GEMM reading hi/lo; fp32 g3 (reuses g buffer); fp32 final agg
    float* g3 = (float*)g;
    gemm_scaled_hl_kernel<<<gemm3_grid, 256, 0, stream>>>(h_hi, h_lo, W3, inv_sqrt, g3, N, HID, CLS);
    agg_final_kernel<<<agg_grid, 256, 0, stream>>>(g3, row_ptr, src_sorted, inv_sqrt,
                                                   b3, (float*)d_out, N);
}

// Round 8
// 540.132 us; speedup vs baseline: 1.0451x; 1.0334x over previous
//
#include <hip/hip_runtime.h>
#include <cstdint>
#include <cstddef>

#define FEAT 512
#define HID 256
#define CLS 40
#define EPS 1e-5f

typedef __attribute__((ext_vector_type(8))) short short8;
typedef __attribute__((ext_vector_type(4))) float f32x4v;

// ---------------- helpers ----------------

__device__ __forceinline__ unsigned short f2bf(float f) {
    union { float f; unsigned u; } v; v.f = f;
    unsigned r = v.u + 0x7FFF + ((v.u >> 16) & 1);   // round-to-nearest-even
    return (unsigned short)(r >> 16);
}
__device__ __forceinline__ float bf2f(unsigned short h) {
    union { unsigned u; float f; } v; v.u = ((unsigned)h) << 16;
    return v.f;
}

typedef const __attribute__((address_space(1))) unsigned int* gas_ptr;
typedef __attribute__((address_space(3))) unsigned int* las_ptr;
__device__ __forceinline__ void lds_load16(const void* g, void* l) {
    __builtin_amdgcn_global_load_lds((gas_ptr)g, (las_ptr)l, 16, 0, 0);
}

__device__ __forceinline__ float4 f4add(float4 a, float4 b) {
    return make_float4(a.x + b.x, a.y + b.y, a.z + b.z, a.w + b.w);
}

// accumulate a bf16x4 row fragment into a float4
__device__ __forceinline__ void accum_bf4(float4& a, ushort4 v) {
    a.x += bf2f(v.x); a.y += bf2f(v.y); a.z += bf2f(v.z); a.w += bf2f(v.w);
}

// ---------------- fused prep: zero counts/fillpos + split W1/W2 + x->bf16 ----------------
// One launch replaces zero_kernel + cvt_w(W1) + cvt_w(W2) + cvt_x.

__global__ __launch_bounds__(256) void prep_cvt_kernel(
        const float* __restrict__ x, const float* __restrict__ W1, const float* __restrict__ W2,
        int* __restrict__ counts, int* __restrict__ fillpos,
        unsigned short* __restrict__ w1hi, unsigned short* __restrict__ w1lo,
        unsigned short* __restrict__ w2hi, unsigned short* __restrict__ w2lo,
        unsigned short* __restrict__ xbf, int N) {
    int i = blockIdx.x * 256 + threadIdx.x;
    const int n0 = N;                 // zero range
    const int n1 = FEAT * HID;        // W1 split+transpose
    const int n2 = HID * HID;         // W2 split+transpose
    const int n3 = N * FEAT / 8;      // x -> bf16 (8 elems/item)
    if (i < n0) { counts[i] = 0; fillpos[i] = 0; return; }
    i -= n0;
    if (i < n1) {
        int k = i / HID, n = i % HID;
        float f = W1[i];
        unsigned short h = f2bf(f);
        w1hi[(size_t)n * FEAT + k] = h;
        w1lo[(size_t)n * FEAT + k] = f2bf(f - bf2f(h));
        return;
    }
    i -= n1;
    if (i < n2) {
        int k = i / HID, n = i % HID;
        float f = W2[i];
        unsigned short h = f2bf(f);
        w2hi[(size_t)n * HID + k] = h;
        w2lo[(size_t)n * HID + k] = f2bf(f - bf2f(h));
        return;
    }
    i -= n2;
    if (i < n3) {
        const float4* xp = (const float4*)x;
        float4 a = xp[2 * i], b = xp[2 * i + 1];
        float f[8] = {a.x, a.y, a.z, a.w, b.x, b.y, b.z, b.w};
        short8 h;
#pragma unroll
        for (int j = 0; j < 8; ++j) h[j] = (short)f2bf(f[j]);
        ((short8*)xbf)[i] = h;
    }
}

// ---------------- CSR build ----------------

__global__ void hist_kernel(const int* __restrict__ dst, int* __restrict__ counts, int E) {
    int e = blockIdx.x * 256 + threadIdx.x;
    if (e < E) atomicAdd(&counts[dst[e]], 1);
}

__global__ void scan_block_kernel(const int* __restrict__ counts, int* __restrict__ row_ptr,
                                  int* __restrict__ blocksums, int n) {
    __shared__ int s[256];
    int tid = threadIdx.x;
    int i = blockIdx.x * 256 + tid;
    int v = (i < n) ? counts[i] : 0;
    s[tid] = v; __syncthreads();
    for (int off = 1; off < 256; off <<= 1) {
        int t = (tid >= off) ? s[tid - off] : 0;
        __syncthreads();
        s[tid] += t;
        __syncthreads();
    }
    if (i < n) row_ptr[i] = s[tid] - v;
    if (tid == 255) blocksums[blockIdx.x] = s[255];
}

// scan_sums folded in: every block redundantly scans blocksums (nb<=256) in LDS.
__global__ void finalize_rowptr_kernel(int* __restrict__ row_ptr, const int* __restrict__ blocksums,
                                       const int* __restrict__ counts, float* __restrict__ inv_sqrt,
                                       int n, int E, int nb) {
    __shared__ int s[256];
    __shared__ int excl[256];
    int tid = threadIdx.x;
    int v = (tid < nb) ? blocksums[tid] : 0;
    s[tid] = v; __syncthreads();
    for (int off = 1; off < 256; off <<= 1) {
        int t = (tid >= off) ? s[tid - off] : 0;
        __syncthreads();
        s[tid] += t;
        __syncthreads();
    }
    excl[tid] = s[tid] - v;
    __syncthreads();
    int i = blockIdx.x * 256 + tid;
    if (i < n) {
        row_ptr[i] += excl[i >> 8];
        inv_sqrt[i] = rsqrtf((float)(counts[i] + 1));
    }
    if (i == 0) row_ptr[n] = E;
}

__global__ void fill_kernel(const int* __restrict__ src, const int* __restrict__ dst,
                            const int* __restrict__ row_ptr, int* __restrict__ fillpos,
                            int* __restrict__ src_sorted, int E) {
    int e = blockIdx.x * 256 + threadIdx.x;
    if (e < E) {
        int d = dst[e];
        int pos = row_ptr[d] + atomicAdd(&fillpos[d], 1);
        src_sorted[pos] = src[e];
    }
}

// ---------------- split-bf16 MFMA GEMM ----------------
// C[row][col] = bf16( (A @ W)[row][col] * inv_sqrt[row] ), W = Whi+Wlo.
// A_SPLIT=true : A = Ahi+Alo (3 MFMAs/pair).   A_SPLIT=false: A = single bf16 (2 MFMAs/pair).
// 128x128 tile, BK template, 4 waves, each wave 64x64 = 4x4 frags of 16x16x32.
// LDS fragment-linear per 16-row m-block (BLK=16*BK ushorts/block); each 32-k chunk is one
// wave-load (64 lanes x 16B via global_load_lds), frag reads are lane*16B ds_read_b128.
// Wt is [n][k] so B-fragments are contiguous 16B runs too.

template<bool A_SPLIT, int BK>
__global__ __launch_bounds__(256) void gemm_mfma_kernel(
        const unsigned short* __restrict__ gAhi, const unsigned short* __restrict__ gAlo,
        const unsigned short* __restrict__ Wthi, const unsigned short* __restrict__ Wtlo,
        const float* __restrict__ inv_sqrt, unsigned short* __restrict__ C,
        int M, int K, int Ncol) {
    constexpr int BLK = 16 * BK;               // ushorts per 16-row block
    __shared__ unsigned short AhiL[128 * BK];
    __shared__ unsigned short AloL[A_SPLIT ? 128 * BK : 4];
    __shared__ unsigned short BhiL[128 * BK], BloL[128 * BK];
    const int tid  = threadIdx.x;
    const int lane = tid & 63;
    const int w    = tid >> 6;        // wave 0..3
    const int wr   = w >> 1, wc = w & 1;
    const int lm   = lane & 15;
    const int lk8  = (lane >> 4) * 8;
    const int bm   = blockIdx.x * 128;
    const int bn   = blockIdx.y * 128;

    f32x4v acc[4][4] = {};

    // --- B staging pointers (wave fills n-blocks 2w, 2w+1, hi+lo) ---
    int nc0 = bn + 16 * (2 * w) + lm;
    int nc1 = bn + 16 * (2 * w + 1) + lm;
    const unsigned short* gB_h0 = Wthi + (size_t)nc0 * K + lk8;
    const unsigned short* gB_h1 = Wthi + (size_t)nc1 * K + lk8;
    const unsigned short* gB_l0 = Wtlo + (size_t)nc0 * K + lk8;
    const unsigned short* gB_l1 = Wtlo + (size_t)nc1 * K + lk8;

    // --- A staging pointers: wave fills m-blocks 2w, 2w+1 (lane i -> ushort i*8) ---
    int ar0 = bm + 16 * (2 * w) + lm;     if (ar0 >= M) ar0 = M - 1;
    int ar1 = bm + 16 * (2 * w + 1) + lm; if (ar1 >= M) ar1 = M - 1;
    const unsigned short* gA_h0 = gAhi + (size_t)ar0 * K + lk8;
    const unsigned short* gA_h1 = gAhi + (size_t)ar1 * K + lk8;
    const unsigned short* gA_l0 = A_SPLIT ? gAlo + (size_t)ar0 * K + lk8 : nullptr;
    const unsigned short* gA_l1 = A_SPLIT ? gAlo + (size_t)ar1 * K + lk8 : nullptr;

    for (int k0 = 0; k0 < K; k0 += BK) {
        // ---- stage A+B: per 32-k chunk kk, one wave-load per (block, operand) ----
#pragma unroll
        for (int kk = 0; kk < BK / 32; ++kk) {
            const int kg = k0 + 32 * kk;
            const int lo = kk * 512;           // ushort offset of 32-k chunk within block
            lds_load16(gA_h0 + kg, &AhiL[(2 * w) * BLK + lo]);
            lds_load16(gA_h1 + kg, &AhiL[(2 * w + 1) * BLK + lo]);
            if (A_SPLIT) {
                lds_load16(gA_l0 + kg, &AloL[(2 * w) * BLK + lo]);
                lds_load16(gA_l1 + kg, &AloL[(2 * w + 1) * BLK + lo]);
            }
            lds_load16(gB_h0 + kg, &BhiL[(2 * w) * BLK + lo]);
            lds_load16(gB_h1 + kg, &BhiL[(2 * w + 1) * BLK + lo]);
            lds_load16(gB_l0 + kg, &BloL[(2 * w) * BLK + lo]);
            lds_load16(gB_l1 + kg, &BloL[(2 * w + 1) * BLK + lo]);
        }
        __syncthreads();

        // ---- compute: one 32-k half at a time ----
#pragma unroll
        for (int half = 0; half < BK / 32; ++half) {
            const int ho = half * 512;
            short8 ah[4], av[4], bh[4], bv[4];
#pragma unroll
            for (int i = 0; i < 4; ++i) {
                int ao = (wr * 4 + i) * BLK + ho + lane * 8;
                int bo = (wc * 4 + i) * BLK + ho + lane * 8;
                ah[i] = *(const short8*)&AhiL[ao];
                if (A_SPLIT) av[i] = *(const short8*)&AloL[ao];
                bh[i] = *(const short8*)&BhiL[bo];
                bv[i] = *(const short8*)&BloL[bo];
            }
#pragma unroll
            for (int i = 0; i < 4; ++i)
#pragma unroll
                for (int j = 0; j < 4; ++j) {
                    acc[i][j] = __builtin_amdgcn_mfma_f32_16x16x32_bf16(ah[i], bh[j], acc[i][j], 0, 0, 0);
                    if (A_SPLIT)
                        acc[i][j] = __builtin_amdgcn_mfma_f32_16x16x32_bf16(av[i], bh[j], acc[i][j], 0, 0, 0);
                    acc[i][j] = __builtin_amdgcn_mfma_f32_16x16x32_bf16(ah[i], bv[j], acc[i][j], 0, 0, 0);
                }
        }
        __syncthreads();
    }

    // ---- epilogue: C/D layout col=lane&15, row=(lane>>4)*4+r ; store bf16 ----
    const int orow_base = bm + wr * 64;
    const int ocol_base = bn + wc * 64 + lm;
    const int rq = (lane >> 4) * 4;
#pragma unroll
    for (int i = 0; i < 4; ++i) {
#pragma unroll
        for (int r = 0; r < 4; ++r) {
            int row = orow_base + i * 16 + rq + r;
            if (row >= M) continue;
            float s = inv_sqrt[row];
            size_t rb = (size_t)row * Ncol;
#pragma unroll
            for (int j = 0; j < 4; ++j)
                C[rb + ocol_base + j * 16] = f2bf(acc[i][j][r] * s);
        }
    }
}

// ---------------- fp32 vector GEMM for layer 3 (A given as hi/lo bf16) ----------------

__global__ __launch_bounds__(256) void gemm_scaled_hl_kernel(
        const unsigned short* __restrict__ Ahi, const unsigned short* __restrict__ Alo,
        const float* __restrict__ W,
        const float* __restrict__ inv_sqrt, float* __restrict__ C,
        int M, int K, int Ncol) {
    __shared__ float As[16][64];
    __shared__ float Ws[16][64];
    int tid = threadIdx.x;
    int tm = tid >> 4;
    int tn = tid & 15;
    int bm = blockIdx.x * 64;
    int bn = blockIdx.y * 64;

    float acc[4][4] = {};

    int lr = tid >> 2;
    int lc = (tid & 3) << 2;
    int wr = tid >> 4;
    int wc = (tid & 15) << 2;
    int arow = bm + lr;
    bool aok = arow < M;
    bool wok = (bn + wc) < Ncol;
    const unsigned short* AhiRow = Ahi + (size_t)arow * K + lc;
    const unsigned short* AloRow = Alo + (size_t)arow * K + lc;

    for (int k0 = 0; k0 < K; k0 += 16) {
        float4 av = make_float4(0.f, 0.f, 0.f, 0.f);
        if (aok) {
            ushort4 hv = *(const ushort4*)(AhiRow + k0);
            ushort4 lv = *(const ushort4*)(AloRow + k0);
            av.x = bf2f(hv.x) + bf2f(lv.x);
            av.y = bf2f(hv.y) + bf2f(lv.y);
            av.z = bf2f(hv.z) + bf2f(lv.z);
            av.w = bf2f(hv.w) + bf2f(lv.w);
        }
        As[lc + 0][lr] = av.x; As[lc + 1][lr] = av.y;
        As[lc + 2][lr] = av.z; As[lc + 3][lr] = av.w;

        float4 wv = make_float4(0.f, 0.f, 0.f, 0.f);
        if (wok) wv = *(const float4*)(W + (size_t)(k0 + wr) * Ncol + bn + wc);
        *(float4*)&Ws[wr][wc] = wv;
        __syncthreads();

#pragma unroll
        for (int k = 0; k < 16; ++k) {
            const float4 a4 = *(const float4*)&As[k][tm << 2];
            const float4 b4 = *(const float4*)&Ws[k][tn << 2];
            float a[4] = {a4.x, a4.y, a4.z, a4.w};
            float b[4] = {b4.x, b4.y, b4.z, b4.w};
#pragma unroll
            for (int i = 0; i < 4; ++i)
#pragma unroll
                for (int j = 0; j < 4; ++j)
                    acc[i][j] = fmaf(a[i], b[j], acc[i][j]);
        }
        __syncthreads();
    }

#pragma unroll
    for (int i = 0; i < 4; ++i) {
        int row = bm + (tm << 2) + i;
        if (row >= M) continue;
        float s = inv_sqrt[row];
        int col = bn + (tn << 2);
        if (col < Ncol) {
            float4 o = make_float4(acc[i][0] * s, acc[i][1] * s, acc[i][2] * s, acc[i][3] * s);
            *(float4*)&C[(size_t)row * Ncol + col] = o;
        }
    }
}

// ---------------- aggregation (H=256): one wave per node; g is bf16, acc fp32 ----------------
// WRITE_LO=false: h output single bf16 (feeds MFMA GEMM).  true: hi/lo pair (feeds fp32 GEMM3).

template<bool WRITE_LO>
__global__ __launch_bounds__(256) void agg_bn_hl_kernel(
        const unsigned short* __restrict__ g, const int* __restrict__ row_ptr,
        const int* __restrict__ srcs, const float* __restrict__ inv_sqrt,
        const float* __restrict__ bias, const float* __restrict__ gamma,
        const float* __restrict__ beta, const float* __restrict__ mean,
        const float* __restrict__ var,
        unsigned short* __restrict__ out_hi, unsigned short* __restrict__ out_lo, int n) {
    int node = (blockIdx.x << 2) + (threadIdx.x >> 6);
    int lane = threadIdx.x & 63;
    if (node >= n) return;
    const ushort4* gp = (const ushort4*)g;   // 64 ushort4 per 256-elem row
    float4 acc0 = make_float4(0.f, 0.f, 0.f, 0.f);
    float4 acc1 = make_float4(0.f, 0.f, 0.f, 0.f);
    accum_bf4(acc0, gp[(size_t)node * 64 + lane]);   // self-loop
    int beg = row_ptr[node];
    int cnt = row_ptr[node + 1] - beg;

    for (int base = 0; base < cnt; base += 64) {
        int m = cnt - base; if (m > 64) m = 64;
        int idx = (lane < m) ? srcs[beg + base + lane] : 0;
        int j = 0;
        for (; j + 8 <= m; j += 8) {
            int s0 = __shfl(idx, j + 0), s1 = __shfl(idx, j + 1);
            int s2 = __shfl(idx, j + 2), s3 = __shfl(idx, j + 3);
            int s4 = __shfl(idx, j + 4), s5 = __shfl(idx, j + 5);
            int s6 = __shfl(idx, j + 6), s7 = __shfl(idx, j + 7);
            ushort4 v0 = gp[(size_t)s0 * 64 + lane];
            ushort4 v1 = gp[(size_t)s1 * 64 + lane];
            ushort4 v2 = gp[(size_t)s2 * 64 + lane];
            ushort4 v3 = gp[(size_t)s3 * 64 + lane];
            ushort4 v4 = gp[(size_t)s4 * 64 + lane];
            ushort4 v5 = gp[(size_t)s5 * 64 + lane];
            ushort4 v6 = gp[(size_t)s6 * 64 + lane];
            ushort4 v7 = gp[(size_t)s7 * 64 + lane];
            accum_bf4(acc0, v0); accum_bf4(acc0, v1);
            accum_bf4(acc0, v2); accum_bf4(acc0, v3);
            accum_bf4(acc1, v4); accum_bf4(acc1, v5);
            accum_bf4(acc1, v6); accum_bf4(acc1, v7);
        }
        for (; j < m; ++j) {
            int s = __shfl(idx, j);
            accum_bf4(acc0, gp[(size_t)s * 64 + lane]);
        }
    }
    float4 acc = f4add(acc0, acc1);

    float inv = inv_sqrt[node];
    float4 b4  = ((const float4*)bias)[lane];
    float4 ga4 = ((const float4*)gamma)[lane];
    float4 be4 = ((const float4*)beta)[lane];
    float4 m4  = ((const float4*)mean)[lane];
    float4 v4  = ((const float4*)var)[lane];
    float4 o;
    o.x = fmaxf((acc.x * inv + b4.x - m4.x) * (ga4.x * rsqrtf(v4.x + EPS)) + be4.x, 0.f);
    o.y = fmaxf((acc.y * inv + b4.y - m4.y) * (ga4.y * rsqrtf(v4.y + EPS)) + be4.y, 0.f);
    o.z = fmaxf((acc.z * inv + b4.z - m4.z) * (ga4.z * rsqrtf(v4.z + EPS)) + be4.z, 0.f);
    o.w = fmaxf((acc.w * inv + b4.w - m4.w) * (ga4.w * rsqrtf(v4.w + EPS)) + be4.w, 0.f);
    ushort4 oh;
    oh.x = f2bf(o.x); oh.y = f2bf(o.y); oh.z = f2bf(o.z); oh.w = f2bf(o.w);
    ((ushort4*)out_hi)[(size_t)node * 64 + lane] = oh;
    if (WRITE_LO) {
        ushort4 ol;
        ol.x = f2bf(o.x - bf2f(oh.x));
        ol.y = f2bf(o.y - bf2f(oh.y));
        ol.z = f2bf(o.z - bf2f(oh.z));
        ol.w = f2bf(o.w - bf2f(oh.w));
        ((ushort4*)out_lo)[(size_t)node * 64 + lane] = ol;
    }
}

// ---------------- final aggregation (C=40): fp32; all 64 lanes stay alive for shfl ----------------

__global__ __launch_bounds__(256) void agg_final_kernel(
        const float* __restrict__ g, const int* __restrict__ row_ptr,
        const int* __restrict__ srcs, const float* __restrict__ inv_sqrt,
        const float* __restrict__ bias, float* __restrict__ out, int n) {
    int node = (blockIdx.x << 2) + (threadIdx.x >> 6);
    int lane = threadIdx.x & 63;
    if (node >= n) return;
    int flane = (lane < CLS) ? lane : 0;       // clamped gather lane; store masked below
    float acc0 = g[(size_t)node * CLS + flane];
    float acc1 = 0.f;
    int beg = row_ptr[node];
    int cnt = row_ptr[node + 1] - beg;

    for (int base = 0; base < cnt; base += 64) {
        int m = cnt - base; if (m > 64) m = 64;
        int idx = (lane < m) ? srcs[beg + base + lane] : 0;
        int j = 0;
        for (; j + 8 <= m; j += 8) {
            int s0 = __shfl(idx, j + 0), s1 = __shfl(idx, j + 1);
            int s2 = __shfl(idx, j + 2), s3 = __shfl(idx, j + 3);
            int s4 = __shfl(idx, j + 4), s5 = __shfl(idx, j + 5);
            int s6 = __shfl(idx, j + 6), s7 = __shfl(idx, j + 7);
            float v0 = g[(size_t)s0 * CLS + flane];
            float v1 = g[(size_t)s1 * CLS + flane];
            float v2 = g[(size_t)s2 * CLS + flane];
            float v3 = g[(size_t)s3 * CLS + flane];
            float v4 = g[(size_t)s4 * CLS + flane];
            float v5 = g[(size_t)s5 * CLS + flane];
            float v6 = g[(size_t)s6 * CLS + flane];
            float v7 = g[(size_t)s7 * CLS + flane];
            acc0 += (v0 + v1) + (v2 + v3);
            acc1 += (v4 + v5) + (v6 + v7);
        }
        for (; j < m; ++j) {
            int s = __shfl(idx, j);
            acc0 += g[(size_t)s * CLS + flane];
        }
    }
    if (lane < CLS)
        out[(size_t)node * CLS + lane] = (acc0 + acc1) * inv_sqrt[node] + bias[lane];
}

// ---------------- launch ----------------

extern "C" void kernel_launch(void* const* d_in, const int* in_sizes, int n_in,
                              void* d_out, int out_size, void* d_ws, size_t ws_size,
                              hipStream_t stream) {
    const float* x     = (const float*)d_in[0];
    const int*   edges = (const int*)d_in[1];
    const float* W1    = (const float*)d_in[2];
    const float* b1    = (const float*)d_in[3];
    const float* W2    = (const float*)d_in[4];
    const float* b2    = (const float*)d_in[5];
    const float* W3    = (const float*)d_in[6];
    const float* b3    = (const float*)d_in[7];
    const float* gamma = (const float*)d_in[8];
    const float* beta  = (const float*)d_in[9];
    const float* mean  = (const float*)d_in[10];
    const float* var   = (const float*)d_in[11];

    const int N = in_sizes[0] / FEAT;   // 50000
    const int E = in_sizes[1] / 2;      // 800000
    const int* src = edges;
    const int* dst = edges + E;

    char* ws = (char*)d_ws;
    auto alloc = [&](size_t bytes) -> char* {
        char* p = ws;
        ws += (bytes + 255) & ~(size_t)255;
        return p;
    };
    int*   counts     = (int*)  alloc((size_t)N * 4);
    int*   fillpos    = (int*)  alloc((size_t)N * 4);
    int*   row_ptr    = (int*)  alloc((size_t)(N + 1) * 4);
    int*   blocksums  = (int*)  alloc(256 * 4);
    float* inv_sqrt   = (float*)alloc((size_t)N * 4);
    int*   src_sorted = (int*)  alloc((size_t)E * 4);
    unsigned short* w1hi = (unsigned short*)alloc((size_t)FEAT * HID * 2);
    unsigned short* w1lo = (unsigned short*)alloc((size_t)FEAT * HID * 2);
    unsigned short* w2hi = (unsigned short*)alloc((size_t)HID * HID * 2);
    unsigned short* w2lo = (unsigned short*)alloc((size_t)HID * HID * 2);
    // g: bf16 for layers 1-2 (25.6 MB); reused as fp32 N*CLS (8 MB) for layer 3
    unsigned short* g    = (unsigned short*)alloc((size_t)N * HID * 2);
    unsigned short* h_hi = (unsigned short*)alloc((size_t)N * HID * 2); // 25.6 MB
    unsigned short* h_lo = (unsigned short*)alloc((size_t)N * HID * 2); // 25.6 MB
    // xbf (N*FEAT bf16 = 51.2 MB) aliases h_hi+h_lo: dead once GEMM1 completes,
    // and agg1 (first writer of h_hi) runs strictly after GEMM1 on the stream.
    unsigned short* xbf  = h_hi;

    int nb = (N + 255) / 256;           // 196
    int eb = (E + 255) / 256;

    // 1) fused prep: zero + W1/W2 split + x->bf16
    int prep_items = N + FEAT * HID + HID * HID + N * FEAT / 8;
    prep_cvt_kernel<<<(prep_items + 255) / 256, 256, 0, stream>>>(
        x, W1, W2, counts, fillpos, w1hi, w1lo, w2hi, w2lo, xbf, N);
    // 2-5) CSR build
    hist_kernel<<<eb, 256, 0, stream>>>(dst, counts, E);
    scan_block_kernel<<<nb, 256, 0, stream>>>(counts, row_ptr, blocksums, N);
    finalize_rowptr_kernel<<<nb, 256, 0, stream>>>(row_ptr, blocksums, counts, inv_sqrt, N, E, nb);
    fill_kernel<<<eb, 256, 0, stream>>>(src, dst, row_ptr, fillpos, src_sorted, E);

    dim3 mfma_grid((N + 127) / 128, HID / 128);
    dim3 gemm3_grid((N + 63) / 64, 1);
    dim3 agg_grid((N + 3) / 4);

    // 6-7) layer 1: A = bf16(x) single (2 MFMAs), BK=64; agg1 -> h single bf16
    gemm_mfma_kernel<false, 64><<<mfma_grid, 256, 0, stream>>>(
        xbf, nullptr, w1hi, w1lo, inv_sqrt, g, N, FEAT, HID);
    agg_bn_hl_kernel<false><<<agg_grid, 256, 0, stream>>>(g, row_ptr, src_sorted, inv_sqrt,
                                                          b1, gamma, beta, mean, var, h_hi, nullptr, N);
    // 8-9) layer 2: A = h1 single bf16 (2 MFMAs), BK=64; agg2 -> h2 hi/lo for fp32 GEMM3
    gemm_mfma_kernel<false, 64><<<mfma_grid, 256, 0, stream>>>(
        h_hi, nullptr, w2hi, w2lo, inv_sqrt, g, N, HID, HID);
    agg_bn_hl_kernel<true><<<agg_grid, 256, 0, stream>>>(g, row_ptr, src_sorted, inv_sqrt,
                                                         b2, gamma, beta, mean, var, h_hi, h_lo, N);
    // 10-11) layer 3: fp32 vector GEMM reading hi/lo; fp32 g3 (reuses g buffer); fp32 final agg
    float* g3 = (float*)g;
    gemm_scaled_hl_kernel<<<gemm3_grid, 256, 0, stream>>>(h_hi, h_lo, W3, inv_sqrt, g3, N, HID, CLS);
    agg_final_kernel<<<agg_grid, 256, 0, stream>>>(g3, row_ptr, src_sorted, inv_sqrt,
                                                   b3, (float*)d_out, N);
}